// Round 9
// baseline (463.818 us; speedup 1.0000x reference)
//
#include <hip/hip_runtime.h>
#include <hip/hip_bf16.h>
#include <math.h>

#define NF 1433
#define NH 16
#define NC 7
#define NCH 45          // ceil(1433/32), odd
#define NBKT_MAX 512    // supports n <= 131072 (bucket = dst>>8)
#define SC2 3072        // LDS-sortable sub-chunk
#define CB 256          // CSR blocks in fused kernel
#define GRID_F 1024     // total fused grid (4 blocks/CU guaranteed resident)

typedef __attribute__((ext_vector_type(8))) short bf16x8;
typedef __attribute__((ext_vector_type(4))) float f32x4;

__device__ __forceinline__ unsigned short f2bf(float f) {
  unsigned int u = __float_as_uint(f);
  unsigned int r = (u + 0x7FFFu + ((u >> 16) & 1u)) >> 16;  // RNE
  return (unsigned short)r;
}
// hot-path convert: let the compiler emit v_cvt_pk_bf16_f32
__device__ __forceinline__ short f2bfs(float f) {
  union { __hip_bfloat16 h; short s; } u;
  u.h = __float2bfloat16(f);
  return u.s;
}
__device__ __forceinline__ unsigned int packbf(float lo, float hi) {
  return (unsigned int)f2bf(lo) | ((unsigned int)f2bf(hi) << 16);
}
// a[i] += 8 bf16 (packed uint4)
__device__ __forceinline__ void acc8(float* a, uint4 r) {
  a[0] += __uint_as_float(r.x << 16); a[1] += __uint_as_float(r.x & 0xffff0000u);
  a[2] += __uint_as_float(r.y << 16); a[3] += __uint_as_float(r.y & 0xffff0000u);
  a[4] += __uint_as_float(r.z << 16); a[5] += __uint_as_float(r.z & 0xffff0000u);
  a[6] += __uint_as_float(r.w << 16); a[7] += __uint_as_float(r.w & 0xffff0000u);
}
// a[i] += c * bf16[i]
__device__ __forceinline__ void acc8f(float* a, uint4 r, float c) {
  a[0] = fmaf(__uint_as_float(r.x << 16), c, a[0]);
  a[1] = fmaf(__uint_as_float(r.x & 0xffff0000u), c, a[1]);
  a[2] = fmaf(__uint_as_float(r.y << 16), c, a[2]);
  a[3] = fmaf(__uint_as_float(r.y & 0xffff0000u), c, a[3]);
  a[4] = fmaf(__uint_as_float(r.z << 16), c, a[4]);
  a[5] = fmaf(__uint_as_float(r.z & 0xffff0000u), c, a[5]);
  a[6] = fmaf(__uint_as_float(r.w << 16), c, a[6]);
  a[7] = fmaf(__uint_as_float(r.w & 0xffff0000u), c, a[7]);
}

// partial barrier over the CB CSR blocks (device-scope, cross-XCD safe)
__device__ __forceinline__ void gbar(int* bar, int idx, int target) {
  __syncthreads();
  if (threadIdx.x == 0) {
    __threadfence();
    __hip_atomic_fetch_add(&bar[idx], 1, __ATOMIC_RELEASE, __HIP_MEMORY_SCOPE_AGENT);
    while (__hip_atomic_load(&bar[idx], __ATOMIC_ACQUIRE, __HIP_MEMORY_SCOPE_AGENT) < target)
      __builtin_amdgcn_s_sleep(2);
  }
  __syncthreads();
}

// ---------------- prep: pack W1 fragments + zero counters/barrier/queue ----
// Wb[(c*64+lane)*8+i] = bf16(W1[k][col]), k = c*32+(lane>>4)*8+i, col = lane&15
__global__ void k_prep(const float* __restrict__ W1, short* __restrict__ Wb,
                       int* __restrict__ bcnt, int* __restrict__ bres,
                       int* __restrict__ bar) {
  int t = blockIdx.x * blockDim.x + threadIdx.x;
  if (t < 16 * NBKT_MAX) { bcnt[t] = 0; bres[t] = 0; }
  if (t < 16) bar[t] = 0;   // bar[0],bar[1] = barriers; bar[8] = gemm work queue
  if (t >= NCH * 64 * 8) return;
  int i = t & 7, l = (t >> 3) & 63, c = t >> 9;
  int g = l >> 4, col = l & 15;
  int k = c * 32 + g * 8 + i;
  float v = (k < NF) ? W1[(size_t)k * NH + col] : 0.f;
  Wb[t] = (short)f2bf(v);
}

// ---------------- fused: CSR build (blocks 0..CB-1) || GEMM1 (work queue) --
__global__ __launch_bounds__(256, 4) void k_fused(
    const float* __restrict__ x, const short* __restrict__ Wb,
    const int* __restrict__ ei, int* __restrict__ bcnt, int* __restrict__ bres,
    int* __restrict__ bar, int* __restrict__ ebuf, int* __restrict__ off,
    int* __restrict__ srcs, float* __restrict__ dis,
    unsigned short* __restrict__ hs1, int n, int E, int nbkt) {
  __shared__ int s_gbase[NBKT_MAX];
  __shared__ int s_gcnt[NBKT_MAX];
  __shared__ int s_h[NBKT_MAX];
  __shared__ int s_lo[NBKT_MAX];
  __shared__ int s_lb[NBKT_MAX];
  __shared__ int s_sc[256];
  __shared__ int s_val[SC2];
  __shared__ unsigned short s_bkt[SC2];

  int blk = blockIdx.x, t = threadIdx.x;

  if (blk < CB) {
    // ================= CSR path =================
    const int* src = ei;
    const int* dst = ei + E;
    int perB = (E + CB - 1) / CB;
    int r0 = blk * perB, r1 = min(E, r0 + perB);

    // --- A1: histogram own region into line-padded global counters
    for (int i = t; i < NBKT_MAX; i += 256) s_h[i] = 0;
    __syncthreads();
    for (int e = r0 + t; e < r1; e += 256)
      atomicAdd(&s_h[((unsigned)dst[e]) >> 8], 1);
    __syncthreads();
    for (int i = t; i < nbkt; i += 256)
      if (s_h[i]) atomicAdd(&bcnt[i * 16], s_h[i]);
    gbar(bar, 0, CB);

    // --- A2 (redundant per block): scan bcnt -> s_gbase/s_gcnt in LDS
    {
      int base = 0;
#pragma unroll
      for (int j = 0; j < 2; ++j) {
        int idx = j * 256 + t;
        int v = (idx < nbkt) ? bcnt[idx * 16] : 0;
        s_gcnt[idx] = v;
        s_sc[t] = v;
        __syncthreads();
        for (int o = 1; o < 256; o <<= 1) {
          int u = (t >= o) ? s_sc[t - o] : 0;
          __syncthreads();
          s_sc[t] += u;
          __syncthreads();
        }
        s_gbase[idx] = base + s_sc[t] - v;
        int tot = s_sc[255];
        __syncthreads();
        base += tot;
      }
    }

    // --- A3: radix-partition own region into ebuf (sub-chunks sorted in LDS)
    for (int c0 = r0; c0 < r1; c0 += SC2) {
      int c1 = min(r1, c0 + SC2);
      int csize = c1 - c0;
      for (int i = t; i < NBKT_MAX; i += 256) s_h[i] = 0;
      __syncthreads();
      for (int e = c0 + t; e < c1; e += 256)
        atomicAdd(&s_h[((unsigned)dst[e]) >> 8], 1);
      __syncthreads();
      int b2 = 0;
#pragma unroll
      for (int j = 0; j < 2; ++j) {
        int idx = j * 256 + t;
        int v = s_h[idx];
        s_sc[t] = v;
        __syncthreads();
        for (int o = 1; o < 256; o <<= 1) {
          int u = (t >= o) ? s_sc[t - o] : 0;
          __syncthreads();
          s_sc[t] += u;
          __syncthreads();
        }
        s_lo[idx] = b2 + s_sc[t] - v;
        int tot = s_sc[255];
        __syncthreads();
        b2 += tot;
      }
      for (int i = t; i < nbkt; i += 256) {
        int cc = s_h[i];
        s_lb[i] = cc ? s_gbase[i] + atomicAdd(&bres[i * 16], cc) : 0;
        s_h[i] = 0;  // reuse as cursor
      }
      __syncthreads();
      for (int e = c0 + t; e < c1; e += 256) {
        unsigned d = (unsigned)dst[e];
        int bk = d >> 8;
        int p = s_lo[bk] + atomicAdd(&s_h[bk], 1);
        s_val[p] = (int)(((d & 255u) << 24) | (unsigned)src[e]);
        s_bkt[p] = (unsigned short)bk;
      }
      __syncthreads();
      for (int i = t; i < csize; i += 256) {
        int bk = s_bkt[i];
        ebuf[s_lb[bk] + (i - s_lo[bk])] = s_val[i];
      }
      __syncthreads();
    }
    gbar(bar, 1, CB);

    // --- B: per-bucket local CSR (off, srcs, dis) from ebuf
    for (int b = blk; b < nbkt; b += CB) {
      int eb = s_gbase[b], ee = eb + s_gcnt[b];
      s_h[t] = 0;
      __syncthreads();
      for (int i = eb + t; i < ee; i += 256)
        atomicAdd(&s_h[((unsigned)ebuf[i]) >> 24], 1);
      __syncthreads();
      int deg = s_h[t];
      s_sc[t] = deg;
      __syncthreads();
      for (int o = 1; o < 256; o <<= 1) {
        int u = (t >= o) ? s_sc[t - o] : 0;
        __syncthreads();
        s_sc[t] += u;
        __syncthreads();
      }
      int excl = s_sc[t] - deg;
      int node = (b << 8) + t;
      if (node < n) {
        off[node] = eb + excl;
        dis[node] = rsqrtf((float)deg + 1.0f);
      }
      s_h[t] = eb + excl;  // fill cursor
      __syncthreads();
      for (int i = eb + t; i < ee; i += 256) {
        unsigned v = (unsigned)ebuf[i];
        int slot = atomicAdd(&s_h[v >> 24], 1);
        srcs[slot] = (int)(v & 0xFFFFFFu);
      }
      __syncthreads();
    }
    if (blk == 0 && t == 0) off[n] = E;
  }

  // ============ GEMM1 work queue (all blocks; CSR blocks join when done) ====
  // hs1 = bf16(x @ W1), unscaled. Wave = one 16-row tile, RT=1, 4-deep
  // chunk prefetch (4 x 32B/lane in flight = 8KB/wave -> BW-bound).
  {
    int l = t & 63;
    int rl = l & 15, g = l >> 4;
    const bf16x8* wp = (const bf16x8*)Wb + l;
    int ntb = (n + 15) >> 4;
    int* wq = &bar[8];
    for (;;) {
      int tb = 0;
      if (l == 0) tb = atomicAdd(wq, 1);
      tb = __shfl(tb, 0);
      if (tb >= ntb) break;
      int row0 = tb << 4;
      int r = row0 + rl;
      int rc = r < n ? r : n - 1;  // clamp; masked at store
      const float* xp = x + (size_t)rc * NF + g * 8;

      f32x4 acc;
#pragma unroll
      for (int j = 0; j < 4; ++j) acc[j] = 0.f;
      float xA[8], xB[8], xC[8], xD[8];

#define LOADC1(BUF, CBX) { int _b = (CBX) * 32;                      \
  _Pragma("unroll") for (int i = 0; i < 8; ++i) BUF[i] = xp[_b + i]; }

#define LOADC1G(BUF, CBX) { int _b = (CBX) * 32;                     \
  _Pragma("unroll") for (int i = 0; i < 8; ++i)                      \
    BUF[i] = (_b + g * 8 + i < NF) ? xp[_b + i] : 0.f; }

#define DOC1(BUF, CC) { bf16x8 _w = wp[(size_t)(CC) * 64]; bf16x8 _a; \
  _Pragma("unroll") for (int i = 0; i < 8; ++i) _a[i] = f2bfs(BUF[i]); \
  acc = __builtin_amdgcn_mfma_f32_16x16x32_bf16(_a, _w, acc, 0, 0, 0); }

      LOADC1(xA, 0);
      LOADC1(xB, 1);
      LOADC1(xC, 2);
      LOADC1(xD, 3);
      int c = 0;
      for (; c + 8 < NCH; c += 4) {
        DOC1(xA, c);     LOADC1(xA, c + 4);
        DOC1(xB, c + 1); LOADC1(xB, c + 5);
        DOC1(xC, c + 2); LOADC1(xC, c + 6);
        DOC1(xD, c + 3); LOADC1(xD, c + 7);
      }
      // c == 40 (NCH=45): buffers hold 40..43; chunk 44 is the guarded tail
      DOC1(xA, c);     LOADC1G(xA, c + 4);
      DOC1(xB, c + 1);
      DOC1(xC, c + 2);
      DOC1(xD, c + 3);
      DOC1(xA, c + 4);
#undef LOADC1
#undef LOADC1G
#undef DOC1

      // D layout (m89): col = lane&15, row_in_tile = (lane>>4)*4 + reg
#pragma unroll
      for (int rr = 0; rr < 4; ++rr) {
        int row = row0 + g * 4 + rr;
        if (row < n) hs1[(size_t)row * NH + rl] = f2bf(acc[rr]);
      }
    }
  }
}

// ---------------- pull1 + bias + relu + GEMM2 fused (16 lanes/node) --------
// hs1 unscaled: acc = sum_s dis[s]*h1[s] + dis[d]*h1[d]; v = relu(dis[d]*acc+b1)
__global__ __launch_bounds__(256) void k_pull1(
    const int* __restrict__ off, const int* __restrict__ srcs,
    const float* __restrict__ dis, const uint4* __restrict__ hs1,
    const float* __restrict__ b1, const float* __restrict__ W2,
    uint4* __restrict__ hs2, int n) {
  int t = blockIdx.x * blockDim.x + threadIdx.x;
  int d = t >> 4;
  if (d >= n) return;
  int sub = t & 15, half = sub & 1, ph = sub >> 1;  // ph in [0,8)
  float dd = dis[d];

  float a[8] = {0.f, 0.f, 0.f, 0.f, 0.f, 0.f, 0.f, 0.f};
  if (ph == 0) acc8f(a, hs1[(size_t)d * 2 + half], dd);  // self loop

  int k = off[d] + ph, k1 = off[d + 1];
  for (; k + 8 < k1; k += 16) {  // 2 independent gathers in flight
    int s0 = srcs[k], s1 = srcs[k + 8];
    float c0 = dis[s0], c1 = dis[s1];
    uint4 r0 = hs1[(size_t)s0 * 2 + half];
    uint4 r1 = hs1[(size_t)s1 * 2 + half];
    acc8f(a, r0, c0);
    acc8f(a, r1, c1);
  }
  if (k < k1) {
    int s = srcs[k];
    acc8f(a, hs1[(size_t)s * 2 + half], dis[s]);
  }

#pragma unroll
  for (int i = 0; i < 8; ++i) {  // reduce over the 8 phases (lane bits 1..3)
    a[i] += __shfl_xor(a[i], 2);
    a[i] += __shfl_xor(a[i], 4);
    a[i] += __shfl_xor(a[i], 8);
  }

  float v[8];
#pragma unroll
  for (int i = 0; i < 8; ++i) v[i] = fmaxf(a[i] * dd + b1[half * 8 + i], 0.f);
  float p[NC];
#pragma unroll
  for (int c = 0; c < NC; ++c) {
    float s = 0.f;
#pragma unroll
    for (int i = 0; i < 8; ++i) s = fmaf(v[i], W2[(half * 8 + i) * NC + c], s);
    p[c] = s;
  }
#pragma unroll
  for (int c = 0; c < NC; ++c) p[c] += __shfl_xor(p[c], 1);  // combine halves
  if (sub == 0) {
    uint4 o;
    o.x = packbf(p[0] * dd, p[1] * dd);
    o.y = packbf(p[2] * dd, p[3] * dd);
    o.z = packbf(p[4] * dd, p[5] * dd);
    o.w = packbf(p[6] * dd, 0.f);  // pad col
    hs2[d] = o;
  }
}

// ---------------- pull2 + bias + relu + log_softmax (8 lanes/node) ---------
__global__ __launch_bounds__(256) void k_pull2(
    const int* __restrict__ off, const int* __restrict__ srcs,
    const float* __restrict__ dis, const uint4* __restrict__ hs2,
    const float* __restrict__ b2, float* __restrict__ out, int n) {
  int t = blockIdx.x * blockDim.x + threadIdx.x;
  int d = t >> 3;
  if (d >= n) return;
  int ph = t & 7;

  float a[8] = {0.f, 0.f, 0.f, 0.f, 0.f, 0.f, 0.f, 0.f};
  if (ph == 0) acc8(a, hs2[d]);  // self loop (hs2 pre-scaled)

  int k = off[d] + ph, k1 = off[d + 1];
  for (; k + 8 < k1; k += 16) {
    int s0 = srcs[k], s1 = srcs[k + 8];
    uint4 r0 = hs2[s0];
    uint4 r1 = hs2[s1];
    acc8(a, r0);
    acc8(a, r1);
  }
  if (k < k1) acc8(a, hs2[srcs[k]]);

#pragma unroll
  for (int i = 0; i < 8; ++i) {
    a[i] += __shfl_xor(a[i], 1);
    a[i] += __shfl_xor(a[i], 2);
    a[i] += __shfl_xor(a[i], 4);
  }
  float dd = dis[d];
  float u[NC];
#pragma unroll
  for (int c = 0; c < NC; ++c) u[c] = fmaxf(a[c] * dd + b2[c], 0.f);
  float m = u[0];
#pragma unroll
  for (int c = 1; c < NC; ++c) m = fmaxf(m, u[c]);
  float sum = 0.f;
#pragma unroll
  for (int c = 0; c < NC; ++c) sum += expf(u[c] - m);
  float lg = logf(sum);
  if (ph < NC) out[(size_t)d * NC + ph] = u[ph] - m - lg;
}

extern "C" void kernel_launch(void* const* d_in, const int* in_sizes, int n_in,
                              void* d_out, int out_size, void* d_ws, size_t ws_size,
                              hipStream_t stream) {
  const float* x  = (const float*)d_in[0];
  const int*   ei = (const int*)d_in[1];
  const float* W1 = (const float*)d_in[2];
  const float* b1 = (const float*)d_in[3];
  const float* W2 = (const float*)d_in[4];
  const float* b2 = (const float*)d_in[5];
  int n = in_sizes[0] / NF;   // 100000
  int E = in_sizes[1] / 2;    // 3200000
  int nbkt = (n + 255) >> 8;  // 391

  // workspace layout (16B-aligned regions)
  char* w = (char*)d_ws;
#define TAKE(ptrty, name, bytes) \
  ptrty name = (ptrty)w; w += ((size_t)(bytes) + 15) & ~(size_t)15;
  TAKE(unsigned short*, hs1,  sizeof(short) * (size_t)n * NH)
  TAKE(uint4*,          hs2,  16 * (size_t)n)
  TAKE(float*,          dis,  sizeof(float) * n)
  TAKE(short*,          Wb,   sizeof(short) * NCH * 64 * 8)
  TAKE(int*,            bcnt, sizeof(int) * 16 * NBKT_MAX)
  TAKE(int*,            bres, sizeof(int) * 16 * NBKT_MAX)
  TAKE(int*,            bar,  sizeof(int) * 16)
  TAKE(int*,            ebuf, sizeof(int) * (size_t)E)
  TAKE(int*,            off,  sizeof(int) * (n + 1))
  TAKE(int*,            srcs, sizeof(int) * (size_t)E)
#undef TAKE
  float* out = (float*)d_out;

  // prep: pack W fragments, zero counters/cursors/barrier/queue
  k_prep<<<(NCH * 64 * 8 + 255) / 256, 256, 0, stream>>>(W1, Wb, bcnt, bres, bar);

  // fused CSR || GEMM1 (grid sized to guaranteed co-residency: 4 blocks/CU)
  k_fused<<<GRID_F, 256, 0, stream>>>(x, Wb, ei, bcnt, bres, bar, ebuf, off,
                                      srcs, dis, hs1, n, E, nbkt);

  k_pull1<<<((size_t)n * 16 + 255) / 256, 256, 0, stream>>>(
      off, srcs, dis, (const uint4*)hs1, b1, W2, hs2, n);
  k_pull2<<<((size_t)n * 8 + 255) / 256, 256, 0, stream>>>(
      off, srcs, dis, hs2, b2, out, n);
}

// Round 10
// 324.121 us; speedup vs baseline: 1.4310x; 1.4310x over previous
//
#include <hip/hip_runtime.h>
#include <hip/hip_bf16.h>
#include <math.h>

#define NF 1433
#define NH 16
#define NC 7
#define NCH 45          // ceil(1433/32), odd
#define NBKT_MAX 512    // supports n <= 131072 (bucket = dst>>8)
#define SC_C 3072       // edges per bscatter block (LDS-sortable chunk)

typedef __attribute__((ext_vector_type(8))) short bf16x8;
typedef __attribute__((ext_vector_type(4))) float f32x4;

__device__ __forceinline__ unsigned short f2bf(float f) {
  unsigned int u = __float_as_uint(f);
  unsigned int r = (u + 0x7FFFu + ((u >> 16) & 1u)) >> 16;  // RNE
  return (unsigned short)r;
}
// hot-path convert (compiler folds pairs into v_cvt_pk_bf16_f32)
__device__ __forceinline__ short f2bfs(float f) {
  union { __hip_bfloat16 h; short s; } u;
  u.h = __float2bfloat16(f);
  return u.s;
}
__device__ __forceinline__ unsigned int packbf(float lo, float hi) {
  return (unsigned int)f2bf(lo) | ((unsigned int)f2bf(hi) << 16);
}
// accumulate 8 bf16 (packed in uint4) into a[0..7]
__device__ __forceinline__ void acc8(float* a, uint4 r) {
  a[0] += __uint_as_float(r.x << 16); a[1] += __uint_as_float(r.x & 0xffff0000u);
  a[2] += __uint_as_float(r.y << 16); a[3] += __uint_as_float(r.y & 0xffff0000u);
  a[4] += __uint_as_float(r.z << 16); a[5] += __uint_as_float(r.z & 0xffff0000u);
  a[6] += __uint_as_float(r.w << 16); a[7] += __uint_as_float(r.w & 0xffff0000u);
}

// ---------------- W1 fragment pack + bcnt zero (fused, independent work) ----
// Wb[(c*64 + lane)*8 + i] = bf16(W1[k][col]), k = c*32 + (lane>>4)*8 + i, col = lane&15
__global__ void k_wpack_zero(const float* __restrict__ W1, short* __restrict__ Wb,
                             int* __restrict__ bcnt) {
  int t = blockIdx.x * blockDim.x + threadIdx.x;
  if (t < 16 * NBKT_MAX) bcnt[t] = 0;
  if (t >= NCH * 64 * 8) return;
  int i = t & 7, l = (t >> 3) & 63, c = t >> 9;
  int g = l >> 4, col = l & 15;
  int k = c * 32 + g * 8 + i;
  float v = (k < NF) ? W1[(size_t)k * NH + col] : 0.f;
  Wb[t] = (short)f2bf(v);
}

// ---------------- bucketed CSR build ----------------
// pass A1: per-block LDS histogram of dst>>8, flush via line-padded atomics
__global__ __launch_bounds__(256) void k_bcount(const int* __restrict__ dst,
                                                int* __restrict__ bcnt,
                                                int E, int nbkt) {
  __shared__ int h[NBKT_MAX];
  int t = threadIdx.x;
  for (int i = t; i < nbkt; i += 256) h[i] = 0;
  __syncthreads();
  int e0 = blockIdx.x * SC_C;
  int e1 = min(E, e0 + SC_C);
  for (int e = e0 + t; e < e1; e += 256)
    atomicAdd(&h[((unsigned)dst[e]) >> 8], 1);
  __syncthreads();
  for (int i = t; i < nbkt; i += 256)
    if (h[i]) atomicAdd(&bcnt[i * 16], h[i]);
}

// pass A2: single-block exclusive scan of bucket sizes -> bbase; init bfill
__global__ void k_bscan(const int* __restrict__ bcnt, int* __restrict__ bbase,
                        int* __restrict__ bfill, int nbkt) {
  __shared__ int sm[NBKT_MAX];
  int t = threadIdx.x;  // blockDim = NBKT_MAX
  int v = (t < nbkt) ? bcnt[t * 16] : 0;
  sm[t] = v;
  __syncthreads();
  for (int o = 1; o < NBKT_MAX; o <<= 1) {
    int u = (t >= o) ? sm[t - o] : 0;
    __syncthreads();
    sm[t] += u;
    __syncthreads();
  }
  if (t < nbkt) {
    int b = sm[t] - v;
    bbase[t] = b;
    bfill[t * 16] = b;
  }
  if (t == nbkt) bbase[nbkt] = sm[t];  // == E
}

// pass A3 (radix-partition): hist -> local scan -> LDS bucket-sort of the
// chunk -> coalesced run writes. One global atomic per (block,bucket).
__global__ __launch_bounds__(256) void k_bscatter(const int* __restrict__ ei,
                                                  int* __restrict__ bfill,
                                                  int* __restrict__ ebuf,
                                                  int E, int nbkt) {
  __shared__ int h[NBKT_MAX];              // hist, then fill cursor
  __shared__ int lo[NBKT_MAX];             // block-local exclusive base
  __shared__ int lb[NBKT_MAX];             // reserved global base
  __shared__ int sc2[256];
  __shared__ int sval[SC_C];
  __shared__ unsigned short sbkt[SC_C];
  const int* src = ei;
  const int* dst = ei + E;
  int t = threadIdx.x;
  for (int i = t; i < NBKT_MAX; i += 256) h[i] = 0;
  __syncthreads();
  int e0 = blockIdx.x * SC_C;
  int e1 = min(E, e0 + SC_C);
  int csize = e1 - e0;
  for (int e = e0 + t; e < e1; e += 256)
    atomicAdd(&h[((unsigned)dst[e]) >> 8], 1);
  __syncthreads();
  // exclusive scan of h[0..512) -> lo (two 256-wide passes)
  int base = 0;
#pragma unroll
  for (int j = 0; j < 2; ++j) {
    int idx = j * 256 + t;
    int v = h[idx];
    sc2[t] = v;
    __syncthreads();
    for (int o = 1; o < 256; o <<= 1) {
      int u = (t >= o) ? sc2[t - o] : 0;
      __syncthreads();
      sc2[t] += u;
      __syncthreads();
    }
    lo[idx] = base + sc2[t] - v;
    int tot = sc2[255];
    __syncthreads();
    base += tot;
  }
  // reserve global ranges, reset cursors
  for (int i = t; i < nbkt; i += 256) {
    int c = h[i];
    lb[i] = c ? atomicAdd(&bfill[i * 16], c) : 0;
    h[i] = 0;
  }
  __syncthreads();
  // sort chunk into LDS by bucket
  for (int e = e0 + t; e < e1; e += 256) {
    unsigned d = (unsigned)dst[e];
    int bk = d >> 8;
    int p = lo[bk] + atomicAdd(&h[bk], 1);
    sval[p] = (int)(((d & 255u) << 24) | (unsigned)src[e]);
    sbkt[p] = (unsigned short)bk;
  }
  __syncthreads();
  // coalesced run writes: consecutive i -> consecutive dest within a run
  for (int i = t; i < csize; i += 256) {
    int bk = sbkt[i];
    ebuf[lb[bk] + (i - lo[bk])] = sval[i];
  }
}

// pass B: one workgroup per bucket -> local CSR (off, srcs) + dis, LDS-local
__global__ __launch_bounds__(256) void k_bcsr(const int* __restrict__ ebuf,
                                              const int* __restrict__ bbase,
                                              int* __restrict__ off,
                                              int* __restrict__ srcs,
                                              float* __restrict__ dis, int n) {
  __shared__ int h[256];
  __shared__ int sc[256];
  int b = blockIdx.x, t = threadIdx.x;
  int eb = bbase[b], ee = bbase[b + 1];
  h[t] = 0;
  __syncthreads();
  for (int i = eb + t; i < ee; i += 256)
    atomicAdd(&h[((unsigned)ebuf[i]) >> 24], 1);
  __syncthreads();
  int deg = h[t];
  sc[t] = deg;
  __syncthreads();
  for (int o = 1; o < 256; o <<= 1) {
    int u = (t >= o) ? sc[t - o] : 0;
    __syncthreads();
    sc[t] += u;
    __syncthreads();
  }
  int excl = sc[t] - deg;
  int node = (b << 8) + t;
  if (node < n) {
    off[node] = eb + excl;
    dis[node] = rsqrtf((float)deg + 1.0f);
  }
  if (b == (int)gridDim.x - 1 && t == 0) off[n] = ee;
  h[t] = eb + excl;  // reuse as fill cursor
  __syncthreads();
  for (int i = eb + t; i < ee; i += 256) {
    unsigned v = (unsigned)ebuf[i];
    int slot = atomicAdd(&h[v >> 24], 1);
    srcs[slot] = (int)(v & 0xFFFFFFu);
  }
}

// ---------------- GEMM1 (MFMA bf16, no LDS, RT=1, 4-deep prefetch) ----------
// hs1 = bf16( (x @ W1) * dis[row] ), row layout [n][16] bf16 (32B rows).
// One 16-row tile per wave; 4 named chunk buffers live simultaneously ->
// 128B/lane in flight (BW-bound, not latency-bound). No waves-per-EU cap:
// the register allocator must keep all 4 buffers resident (expect ~70-90 VGPR).
__global__ __launch_bounds__(256) void k_gemm1(
    const float* __restrict__ x, const short* __restrict__ Wb,
    const float* __restrict__ dis, unsigned short* __restrict__ hs1, int n) {
  int l = threadIdx.x & 63;
  int wid = (blockIdx.x * blockDim.x + threadIdx.x) >> 6;  // global wave id
  int ntb = (n + 15) >> 4;
  if (wid >= ntb) return;
  int row0 = wid << 4;
  int rl = l & 15, g = l >> 4;

  int r = row0 + rl;
  int rc = r < n ? r : n - 1;  // clamp; masked at store
  const float* xp = x + (size_t)rc * NF + g * 8;
  const bf16x8* wp = (const bf16x8*)Wb + l;

  f32x4 acc;
#pragma unroll
  for (int j = 0; j < 4; ++j) acc[j] = 0.f;
  float xA[8], xB[8], xC[8], xD[8];  // named 4-deep buffers, static indexing

#define LOADC1(BUF, CBX) { int _b = (CBX) * 32;                      \
  _Pragma("unroll") for (int i = 0; i < 8; ++i) BUF[i] = xp[_b + i]; }

#define LOADC1G(BUF, CBX) { int _b = (CBX) * 32;                     \
  _Pragma("unroll") for (int i = 0; i < 8; ++i)                      \
    BUF[i] = (_b + g * 8 + i < NF) ? xp[_b + i] : 0.f; }

#define DOC1(BUF, CC) { bf16x8 _w = wp[(size_t)(CC) * 64]; bf16x8 _a; \
  _Pragma("unroll") for (int i = 0; i < 8; ++i) _a[i] = f2bfs(BUF[i]); \
  acc = __builtin_amdgcn_mfma_f32_16x16x32_bf16(_a, _w, acc, 0, 0, 0); }

  LOADC1(xA, 0);
  LOADC1(xB, 1);
  LOADC1(xC, 2);
  LOADC1(xD, 3);
  int c = 0;
  for (; c + 8 < NCH; c += 4) {
    DOC1(xA, c);     LOADC1(xA, c + 4);
    DOC1(xB, c + 1); LOADC1(xB, c + 5);
    DOC1(xC, c + 2); LOADC1(xC, c + 6);
    DOC1(xD, c + 3); LOADC1(xD, c + 7);
  }
  // c == 40 (NCH=45): buffers hold chunks 40..43; chunk 44 is the guarded tail
  DOC1(xA, c);     LOADC1G(xA, c + 4);
  DOC1(xB, c + 1);
  DOC1(xC, c + 2);
  DOC1(xD, c + 3);
  DOC1(xA, c + 4);
#undef LOADC1
#undef LOADC1G
#undef DOC1

  // D layout (m89): col = lane&15, row_in_tile = (lane>>4)*4 + reg
#pragma unroll
  for (int rr = 0; rr < 4; ++rr) {
    int row = row0 + g * 4 + rr;
    if (row < n) hs1[(size_t)row * NH + rl] = f2bf(acc[rr] * dis[row]);
  }
}

// ---------------- pull layer 1 + bias + relu + GEMM2 fused (16 lanes/node) --
// bit0 = column half (16B), bits1-3 = edge phase (mod 8).
__global__ __launch_bounds__(256) void k_pull1(
    const int* __restrict__ off, const int* __restrict__ srcs,
    const float* __restrict__ dis, const uint4* __restrict__ hs1,
    const float* __restrict__ b1, const float* __restrict__ W2,
    uint4* __restrict__ hs2, int n) {
  int t = blockIdx.x * blockDim.x + threadIdx.x;
  int d = t >> 4;
  if (d >= n) return;
  int sub = t & 15, half = sub & 1, ph = sub >> 1;  // ph in [0,8)

  float a[8] = {0.f, 0.f, 0.f, 0.f, 0.f, 0.f, 0.f, 0.f};
  if (ph == 0) acc8(a, hs1[(size_t)d * 2 + half]);  // self loop, once per half

  int k = off[d] + ph, k1 = off[d + 1];
  for (; k + 8 < k1; k += 16) {  // 2 independent gathers in flight
    int s0 = srcs[k], s1 = srcs[k + 8];
    uint4 r0 = hs1[(size_t)s0 * 2 + half];
    uint4 r1 = hs1[(size_t)s1 * 2 + half];
    acc8(a, r0);
    acc8(a, r1);
  }
  if (k < k1) acc8(a, hs1[(size_t)srcs[k] * 2 + half]);

#pragma unroll
  for (int i = 0; i < 8; ++i) {  // reduce over the 8 phases (lane bits 1..3)
    a[i] += __shfl_xor(a[i], 2);
    a[i] += __shfl_xor(a[i], 4);
    a[i] += __shfl_xor(a[i], 8);
  }

  // fused epilogue: v = relu(a*dis + b1), p = v @ W2 (half each), combine
  float dd = dis[d];
  float v[8];
#pragma unroll
  for (int i = 0; i < 8; ++i) v[i] = fmaxf(a[i] * dd + b1[half * 8 + i], 0.f);
  float p[NC];
#pragma unroll
  for (int c = 0; c < NC; ++c) {
    float s = 0.f;
#pragma unroll
    for (int i = 0; i < 8; ++i) s = fmaf(v[i], W2[(half * 8 + i) * NC + c], s);
    p[c] = s;
  }
#pragma unroll
  for (int c = 0; c < NC; ++c) p[c] += __shfl_xor(p[c], 1);  // combine halves
  if (sub == 0) {
    uint4 o;
    o.x = packbf(p[0] * dd, p[1] * dd);
    o.y = packbf(p[2] * dd, p[3] * dd);
    o.z = packbf(p[4] * dd, p[5] * dd);
    o.w = packbf(p[6] * dd, 0.f);  // pad col
    hs2[d] = o;
  }
}

// ---------------- pull layer 2 + bias + relu + log_softmax (8 lanes/node) ---
__global__ __launch_bounds__(256) void k_pull2(
    const int* __restrict__ off, const int* __restrict__ srcs,
    const float* __restrict__ dis, const uint4* __restrict__ hs2,
    const float* __restrict__ b2, float* __restrict__ out, int n) {
  int t = blockIdx.x * blockDim.x + threadIdx.x;
  int d = t >> 3;
  if (d >= n) return;
  int ph = t & 7;

  float a[8] = {0.f, 0.f, 0.f, 0.f, 0.f, 0.f, 0.f, 0.f};
  if (ph == 0) acc8(a, hs2[d]);  // self loop once

  int k = off[d] + ph, k1 = off[d + 1];
  for (; k + 8 < k1; k += 16) {
    int s0 = srcs[k], s1 = srcs[k + 8];
    uint4 r0 = hs2[s0];
    uint4 r1 = hs2[s1];
    acc8(a, r0);
    acc8(a, r1);
  }
  if (k < k1) acc8(a, hs2[srcs[k]]);

#pragma unroll
  for (int i = 0; i < 8; ++i) {  // reduce across the 8 phase lanes
    a[i] += __shfl_xor(a[i], 1);
    a[i] += __shfl_xor(a[i], 2);
    a[i] += __shfl_xor(a[i], 4);
  }
  float dd = dis[d];
  float u[NC];
#pragma unroll
  for (int c = 0; c < NC; ++c) u[c] = fmaxf(a[c] * dd + b2[c], 0.f);
  float m = u[0];
#pragma unroll
  for (int c = 1; c < NC; ++c) m = fmaxf(m, u[c]);
  float sum = 0.f;
#pragma unroll
  for (int c = 0; c < NC; ++c) sum += expf(u[c] - m);
  float lg = logf(sum);
  if (ph < NC) out[(size_t)d * NC + ph] = u[ph] - m - lg;
}

extern "C" void kernel_launch(void* const* d_in, const int* in_sizes, int n_in,
                              void* d_out, int out_size, void* d_ws, size_t ws_size,
                              hipStream_t stream) {
  const float* x  = (const float*)d_in[0];
  const int*   ei = (const int*)d_in[1];
  const float* W1 = (const float*)d_in[2];
  const float* b1 = (const float*)d_in[3];
  const float* W2 = (const float*)d_in[4];
  const float* b2 = (const float*)d_in[5];
  int n = in_sizes[0] / NF;   // 100000
  int E = in_sizes[1] / 2;    // 3200000
  int nbkt = (n + 255) >> 8;  // 391

  // workspace layout (each region 16B-aligned)
  char* w = (char*)d_ws;
#define TAKE(ptrty, name, bytes) \
  ptrty name = (ptrty)w; w += ((size_t)(bytes) + 15) & ~(size_t)15;
  TAKE(unsigned short*, hs1,  sizeof(short) * (size_t)n * NH)
  TAKE(uint4*,          hs2,  16 * (size_t)n)
  TAKE(float*,          dis,  sizeof(float) * n)
  TAKE(short*,          Wb,   sizeof(short) * NCH * 64 * 8)
  TAKE(int*,            bcnt, sizeof(int) * 16 * NBKT_MAX)
  TAKE(int*,            bfill,sizeof(int) * 16 * NBKT_MAX)
  TAKE(int*,            bbase,sizeof(int) * (NBKT_MAX + 1))
  TAKE(int*,            ebuf, sizeof(int) * (size_t)E)
  TAKE(int*,            off,  sizeof(int) * (n + 1))
  TAKE(int*,            srcs, sizeof(int) * (size_t)E)
#undef TAKE
  float* out = (float*)d_out;

  int nsb = (E + SC_C - 1) / SC_C;  // 1042

  // independent prep (also zeroes bcnt)
  k_wpack_zero<<<(NCH * 64 * 8 + 255) / 256, 256, 0, stream>>>(W1, Wb, bcnt);

  // bucketed CSR build
  k_bcount<<<nsb, 256, 0, stream>>>(ei + E, bcnt, E, nbkt);
  k_bscan<<<1, NBKT_MAX, 0, stream>>>(bcnt, bbase, bfill, nbkt);
  k_bscatter<<<nsb, 256, 0, stream>>>(ei, bfill, ebuf, E, nbkt);
  k_bcsr<<<nbkt, 256, 0, stream>>>(ebuf, bbase, off, srcs, dis, n);

  // features
  int ntb = (n + 15) >> 4;  // 6250 wave-tiles
  k_gemm1<<<(ntb * 64 + 255) / 256, 256, 0, stream>>>(x, Wb, dis, hs1, n);
  k_pull1<<<((size_t)n * 16 + 255) / 256, 256, 0, stream>>>(
      off, srcs, dis, (const uint4*)hs1, b1, W2, hs2, n);
  k_pull2<<<((size_t)n * 8 + 255) / 256, 256, 0, stream>>>(
      off, srcs, dis, hs2, b2, out, n);
}